// Round 3
// baseline (1142.933 us; speedup 1.0000x reference)
//
#include <hip/hip_runtime.h>
#include <cstdint>

// LlamaSmoothquantMLP on MI355X (gfx950).
//
// Round 3: LDS-BW-bound diagnosis. Per K-tile the CU moves 2x the tile bytes
// through LDS (A shared by 4 N-waves, B by M-waves) -> 768 cyc LDS vs 582 cyc
// MFMA: ceiling 76%. Fixes:
//  - round-1's EXACT 8-slot pair-XOR LDS layout (the only one that measured
//    SQ_LDS_BANK_CONFLICT = 0), BK=64 rounds; the 64B-half over-fetch is
//    absorbed by L2 because the sibling half is staged one iteration later.
//  - 3-round rotation, stage r+2 while computing r, counted WAIT_VM(6)
//    (never 0 mid-loop), ONE raw s_barrier per round -> ~2 iterations of
//    load flight.
//  - 256-thread blocks, 72 KiB LDS -> 2 blocks/CU: cross-block overlap hides
//    each block's barrier/wait bubbles. k_down grid 32x16=512 = exactly 2/CU.
//
// GEMMs: A [M,K] row-major, B [N,K] row-major. MFMA v_mfma_i32_32x32x32_i8.
// C/D layout m74/m101 (verified in prior rounds).

typedef int v4i  __attribute__((ext_vector_type(4)));
typedef int v16i __attribute__((ext_vector_type(16)));

typedef const void __attribute__((address_space(1)))* gas_ptr;
typedef void __attribute__((address_space(3)))* las_ptr;

static constexpr int M_TOT = 4096;   // B*S
static constexpr int HDIM  = 4096;
static constexpr int IDIM  = 11008;

#define MFMA_I8(a, b, c) __builtin_amdgcn_mfma_i32_32x32x32_i8((a), (b), (c), 0, 0, 0)
#define BAR()        asm volatile("s_barrier" ::: "memory")
#define WAIT_VM(N)   asm volatile("s_waitcnt vmcnt(" #N ")" ::: "memory")
#define SETPRIO(P)   __builtin_amdgcn_s_setprio(P)

__device__ __forceinline__ void gload16(const int8_t* g, int8_t* l) {
  __builtin_amdgcn_global_load_lds((gas_ptr)g, (las_ptr)l, 16, 0, 0);
}

// ---------------- LDS tile geometry (BK = 64 bytes per row) ----------------
// Round-1's exact layout (measured SQ_LDS_BANK_CONFLICT = 0).
// Chunk (row, c) c=0..3 lives at byte pair*128 + slot*16,
//   pair = row>>1, slot = ((c<<1)|(row&1)) ^ (pair&7).
// Staging writes LDS linearly (global_load_lds dest = base + lane*16); the
// *global source* is pre-inverse-swizzled via relmap64.
__device__ __forceinline__ v4i frag64(const int8_t* lds, int row, int c) {
  const int pair = row >> 1;
  const int slot = ((c << 1) | (row & 1)) ^ (pair & 7);
  return *(const v4i*)(lds + pair * 128 + slot * 16);
}

__device__ __forceinline__ void relmap64(int rel, int& row, int& col) {
  const int pair = rel >> 3;
  const int sl = (rel & 7) ^ (pair & 7);
  row = 2 * pair + (sl & 1);
  col = (sl >> 1) * 16;
}

// ---------------- pack int32 -> int8, all four tensors in one dispatch ------
__device__ __forceinline__ void pack16(const int* __restrict__ src,
                                       int8_t* __restrict__ dst, int t) {
  const int4* s = (const int4*)(src) + t * 4;
  int4 v0 = s[0], v1 = s[1], v2 = s[2], v3 = s[3];
  int p0 = (v0.x & 0xff) | ((v0.y & 0xff) << 8) | ((v0.z & 0xff) << 16) | (v0.w << 24);
  int p1 = (v1.x & 0xff) | ((v1.y & 0xff) << 8) | ((v1.z & 0xff) << 16) | (v1.w << 24);
  int p2 = (v2.x & 0xff) | ((v2.y & 0xff) << 8) | ((v2.z & 0xff) << 16) | (v2.w << 24);
  int p3 = (v3.x & 0xff) | ((v3.y & 0xff) << 8) | ((v3.z & 0xff) << 16) | (v3.w << 24);
  ((int4*)dst)[t] = make_int4(p0, p1, p2, p3);
}

static constexpr int CX = (M_TOT * HDIM) / 16;            // 1,048,576
static constexpr int CW = (IDIM * HDIM) / 16;             // 2,818,048
static constexpr int CTOT = CX + 3 * CW;                  // 9,502,720

__global__ __launch_bounds__(256) void k_pack_all(
    const int* __restrict__ X32, const int* __restrict__ Wg32,
    const int* __restrict__ Wu32, const int* __restrict__ Wd32,
    int8_t* __restrict__ Xp, int8_t* __restrict__ Wgp,
    int8_t* __restrict__ Wup, int8_t* __restrict__ Wdp) {
  int t = blockIdx.x * blockDim.x + threadIdx.x;
  if (t >= CTOT) return;
  if (t < CX)               { pack16(X32,  Xp,  t); return; }
  t -= CX;
  if (t < CW)               { pack16(Wg32, Wgp, t); return; }
  t -= CW;
  if (t < CW)               { pack16(Wu32, Wup, t); return; }
  t -= CW;
  pack16(Wd32, Wdp, t);
}

// ---------------- gate+up fused GEMM ----------------
// Block 128M x 128N, 256 thr (4 waves, 1Mx4N), wave tile 128M x 32N.
// Round buffer 24 KiB: A [0,8K) 128 rows, G [8K,16K), U [16K,24K).
// 3-round rotation = 72 KiB -> 2 blocks/CU.
__global__ __launch_bounds__(256, 2) void k_gateup(
    const int8_t* __restrict__ X,
    const int8_t* __restrict__ Wg,
    const int8_t* __restrict__ Wu,
    const float* __restrict__ gate_a, const float* __restrict__ gate_b,
    const float* __restrict__ up_a,   const float* __restrict__ up_b,
    const float* __restrict__ down_scale,
    int8_t* __restrict__ Q) {
  __shared__ __align__(16) int8_t lds8[3 * 24576];   // 72 KiB

  const int tid  = threadIdx.x;
  const int lane = tid & 63;
  const int wave = tid >> 6;
  const int wn   = wave;            // 0..3 : N quarter (32 cols)
  const int half = lane >> 5;
  const int ln31 = lane & 31;

  const int m0 = blockIdx.x * 128;
  const int n0 = blockIdx.y * 128;

  const int8_t* Ab = X  + (size_t)m0 * HDIM;
  const int8_t* Gb = Wg + (size_t)n0 * HDIM;
  const int8_t* Ub = Wu + (size_t)n0 * HDIM;

  // per-thread inverse-swizzled global source offsets (tile = 128 rows x 64B
  // = 512 chunks; this thread stages chunks tid and tid+256 of each region)
  int r0, c0, r1, c1;
  relmap64(tid,       r0, c0);
  relmap64(tid + 256, r1, c1);
  const size_t o0 = (size_t)r0 * HDIM + c0;
  const size_t o1 = (size_t)r1 * HDIM + c1;
  const int l0 = tid * 16;
  const int l1 = (tid + 256) * 16;

  v16i accG[4], accU[4];
#pragma unroll
  for (int i = 0; i < 4; ++i)
#pragma unroll
    for (int e = 0; e < 16; ++e) { accG[i][e] = 0; accU[i][e] = 0; }

  const int rB = wn * 32 + ln31;

#define GU_STAGE(rr, bb)                                        \
  {                                                             \
    int8_t* sb = &lds8[(bb) * 24576];                           \
    const size_t ks = (size_t)(rr) * 64;                        \
    gload16(Ab + ks + o0, sb + l0);                             \
    gload16(Ab + ks + o1, sb + l1);                             \
    gload16(Gb + ks + o0, sb + 8192 + l0);                      \
    gload16(Gb + ks + o1, sb + 8192 + l1);                      \
    gload16(Ub + ks + o0, sb + 16384 + l0);                     \
    gload16(Ub + ks + o1, sb + 16384 + l1);                     \
  }

  // prologue: stage rounds 0,1; publish round 0.
  GU_STAGE(0, 0)
  GU_STAGE(1, 1)
  WAIT_VM(6);
  BAR();

  const int NT = HDIM / 64;  // 64 rounds
  int bc = 0;                // consume buffer
  int bs = 2;                // stage buffer (round r+2)
  for (int r = 0; r < NT; ++r) {
    if (r + 2 < NT) GU_STAGE(r + 2, bs)

    const int8_t* bufA = &lds8[bc * 24576];
    const int8_t* bufG = bufA + 8192;
    const int8_t* bufU = bufA + 16384;
    SETPRIO(1);
#pragma unroll
    for (int ks = 0; ks < 2; ++ks) {
      const int c = 2 * ks + half;
      v4i a0 = frag64(bufA, ln31,      c);
      v4i a1 = frag64(bufA, ln31 + 32, c);
      v4i a2 = frag64(bufA, ln31 + 64, c);
      v4i a3 = frag64(bufA, ln31 + 96, c);
      v4i gg = frag64(bufG, rB, c);
      v4i uu = frag64(bufU, rB, c);
      accG[0] = MFMA_I8(a0, gg, accG[0]);
      accU[0] = MFMA_I8(a0, uu, accU[0]);
      accG[1] = MFMA_I8(a1, gg, accG[1]);
      accU[1] = MFMA_I8(a1, uu, accU[1]);
      accG[2] = MFMA_I8(a2, gg, accG[2]);
      accU[2] = MFMA_I8(a2, uu, accU[2]);
      accG[3] = MFMA_I8(a3, gg, accG[3]);
      accU[3] = MFMA_I8(a3, uu, accU[3]);
    }
    SETPRIO(0);

    // publish round r+1: its 6 loads are the oldest outstanding; rounds r+2
    // (6 more) may stay in flight. Tail drains 0.
    if (r + 2 < NT)      { WAIT_VM(6); }
    else if (r + 1 < NT) { WAIT_VM(0); }
    if (r + 1 < NT) BAR();

    bc = (bc == 2) ? 0 : bc + 1;
    bs = (bs == 2) ? 0 : bs + 1;
  }
#undef GU_STAGE

  const float ga = gate_a[0];
  const float ua = up_a[0];
  const float inv_ds = 1.0f / down_scale[0];
  const int n = n0 + wn * 32 + ln31;
  const float gb = gate_b[n];
  const float ub = up_b[n];

#pragma unroll
  for (int tm = 0; tm < 4; ++tm) {
#pragma unroll
    for (int r = 0; r < 16; ++r) {
      // C/D layout (m74/m101): col=lane&31, row=(r&3)+8*(r>>2)+4*(lane>>5)
      const int row_l = (r & 3) + 8 * (r >> 2) + 4 * half;
      const int m = m0 + tm * 32 + row_l;
      const float g = (float)accG[tm][r] * ga + gb;
      const float u = (float)accU[tm][r] * ua + ub;
      const float sg = g / (1.0f + __expf(-g));
      const float inter = sg * u;
      float qf = rintf(inter * inv_ds);
      qf = fminf(127.0f, fmaxf(-128.0f, qf));
      Q[(size_t)m * IDIM + n] = (int8_t)qf;
    }
  }
}

// ---------------- down GEMM ----------------
// Block 128M x 256N, 256 thr (4 waves, 1Mx4N), wave tile 128M x 64N.
// Round buffer 24 KiB: A [0,8K) 128 rows, B [8K,24K) 256 rows.
// 3-round rotation = 72 KiB -> 2 blocks/CU. Grid 32x16 = 512 = exactly 2/CU.
__global__ __launch_bounds__(256, 2) void k_down(
    const int8_t* __restrict__ Qm,
    const int8_t* __restrict__ Wd,
    const float* __restrict__ down_a, const float* __restrict__ down_b,
    float* __restrict__ Out) {
  __shared__ __align__(16) int8_t lds8[3 * 24576];   // 72 KiB

  const int tid  = threadIdx.x;
  const int lane = tid & 63;
  const int wave = tid >> 6;
  const int wn   = wave;            // 0..3 : N quarter (64 cols)
  const int half = lane >> 5;
  const int ln31 = lane & 31;

  const int m0 = blockIdx.x * 128;
  const int n0 = blockIdx.y * 256;

  const int8_t* Ab = Qm + (size_t)m0 * IDIM;
  const int8_t* Bb = Wd + (size_t)n0 * IDIM;

  // A tile: 128 rows x 64B = 512 chunks -> 2 loads/thread.
  // B tile: 256 rows x 64B = 1024 chunks -> 4 loads/thread.
  int ra0, ca0, ra1, ca1;
  relmap64(tid,       ra0, ca0);
  relmap64(tid + 256, ra1, ca1);
  const size_t oa0 = (size_t)ra0 * IDIM + ca0;
  const size_t oa1 = (size_t)ra1 * IDIM + ca1;
  int rb0, cb0, rb1, cb1, rb2, cb2, rb3, cb3;
  relmap64(tid,       rb0, cb0);
  relmap64(tid + 256, rb1, cb1);
  relmap64(tid + 512, rb2, cb2);
  relmap64(tid + 768, rb3, cb3);
  const size_t ob0 = (size_t)rb0 * IDIM + cb0;
  const size_t ob1 = (size_t)rb1 * IDIM + cb1;
  const size_t ob2 = (size_t)rb2 * IDIM + cb2;
  const size_t ob3 = (size_t)rb3 * IDIM + cb3;
  const int l0 = tid * 16;
  const int l1 = (tid + 256) * 16;
  const int l2 = (tid + 512) * 16;
  const int l3 = (tid + 768) * 16;

  v16i acc[4][2];
#pragma unroll
  for (int i = 0; i < 4; ++i)
#pragma unroll
    for (int j = 0; j < 2; ++j)
#pragma unroll
      for (int e = 0; e < 16; ++e) acc[i][j][e] = 0;

  const int rB = wn * 64 + ln31;

#define DN_STAGE(rr, bb)                                        \
  {                                                             \
    int8_t* sb = &lds8[(bb) * 24576];                           \
    const size_t ks = (size_t)(rr) * 64;                        \
    gload16(Ab + ks + oa0, sb + l0);                            \
    gload16(Ab + ks + oa1, sb + l1);                            \
    gload16(Bb + ks + ob0, sb + 8192 + l0);                     \
    gload16(Bb + ks + ob1, sb + 8192 + l1);                     \
    gload16(Bb + ks + ob2, sb + 8192 + l2);                     \
    gload16(Bb + ks + ob3, sb + 8192 + l3);                     \
  }

  DN_STAGE(0, 0)
  DN_STAGE(1, 1)
  WAIT_VM(6);
  BAR();

  const int NT = IDIM / 64;  // 172 rounds
  int bc = 0;
  int bs = 2;
  for (int r = 0; r < NT; ++r) {
    if (r + 2 < NT) DN_STAGE(r + 2, bs)

    const int8_t* bufA = &lds8[bc * 24576];
    const int8_t* bufB = bufA + 8192;
    SETPRIO(1);
#pragma unroll
    for (int ks = 0; ks < 2; ++ks) {
      const int c = 2 * ks + half;
      v4i a0 = frag64(bufA, ln31,      c);
      v4i a1 = frag64(bufA, ln31 + 32, c);
      v4i a2 = frag64(bufA, ln31 + 64, c);
      v4i a3 = frag64(bufA, ln31 + 96, c);
      v4i b0 = frag64(bufB, rB,      c);
      v4i b1 = frag64(bufB, rB + 32, c);
      acc[0][0] = MFMA_I8(a0, b0, acc[0][0]);
      acc[0][1] = MFMA_I8(a0, b1, acc[0][1]);
      acc[1][0] = MFMA_I8(a1, b0, acc[1][0]);
      acc[1][1] = MFMA_I8(a1, b1, acc[1][1]);
      acc[2][0] = MFMA_I8(a2, b0, acc[2][0]);
      acc[2][1] = MFMA_I8(a2, b1, acc[2][1]);
      acc[3][0] = MFMA_I8(a3, b0, acc[3][0]);
      acc[3][1] = MFMA_I8(a3, b1, acc[3][1]);
    }
    SETPRIO(0);

    if (r + 2 < NT)      { WAIT_VM(6); }
    else if (r + 1 < NT) { WAIT_VM(0); }
    if (r + 1 < NT) BAR();

    bc = (bc == 2) ? 0 : bc + 1;
    bs = (bs == 2) ? 0 : bs + 1;
  }
#undef DN_STAGE

  const float da = down_a[0];
#pragma unroll
  for (int tn = 0; tn < 2; ++tn) {
    const int n = n0 + wn * 64 + tn * 32 + ln31;
    const float db = down_b[n];
#pragma unroll
    for (int tm = 0; tm < 4; ++tm) {
#pragma unroll
      for (int r = 0; r < 16; ++r) {
        const int row_l = (r & 3) + 8 * (r >> 2) + 4 * half;
        const int m = m0 + tm * 32 + row_l;
        Out[(size_t)m * HDIM + n] = (float)acc[tm][tn][r] * da + db;
      }
    }
  }
}

extern "C" void kernel_launch(void* const* d_in, const int* in_sizes, int n_in,
                              void* d_out, int out_size, void* d_ws, size_t ws_size,
                              hipStream_t stream) {
  const int* X32        = (const int*)d_in[0];
  const int* Wg32       = (const int*)d_in[1];
  const int* Wu32       = (const int*)d_in[2];
  const int* Wd32       = (const int*)d_in[3];
  const float* gate_a   = (const float*)d_in[4];
  const float* gate_b   = (const float*)d_in[5];
  const float* up_a     = (const float*)d_in[6];
  const float* up_b     = (const float*)d_in[7];
  const float* down_a   = (const float*)d_in[8];
  const float* down_b   = (const float*)d_in[9];
  const float* down_scale = (const float*)d_in[10];
  float* Out = (float*)d_out;

  const size_t nX = (size_t)M_TOT * HDIM;
  const size_t nW = (size_t)IDIM * HDIM;

  // Workspace: Q | Xp | Wgp | Wup | Wdp  (~197 MB)
  int8_t* Q   = (int8_t*)d_ws;
  int8_t* Xp  = Q   + nW;
  int8_t* Wgp = Xp  + nX;
  int8_t* Wup = Wgp + nW;
  int8_t* Wdp = Wup + nW;

  k_pack_all<<<(CTOT + 255) / 256, 256, 0, stream>>>(X32, Wg32, Wu32, Wd32,
                                                     Xp, Wgp, Wup, Wdp);

  k_gateup<<<dim3(M_TOT / 128, IDIM / 128), dim3(256), 0, stream>>>(
      Xp, Wgp, Wup, gate_a, gate_b, up_a, up_b, down_scale, Q);

  k_down<<<dim3(M_TOT / 128, HDIM / 256), dim3(256), 0, stream>>>(
      Q, Wdp, down_a, down_b, Out);
}